// Round 6
// baseline (1498.781 us; speedup 1.0000x reference)
//
#include <hip/hip_runtime.h>
#include <math.h>

// SelfModifyingBlock (TTT inner loop) — round 6: 128x128 tiles (GEMM+wgrad, split-K 49),
// bf16 x pre-convert (adaptive), fast gelu/gelu' in gradient-only paths.

#define BB    16
#define CC    256
#define HWW   3136
#define NTOT  (BB*HWW)        // 50176
#define HIDD  512
#define NGRP  8
#define GMSZ  (64*HWW)
#define C4    64
#define LRATE 0.01f
#define SKW   49
#define WCHUNK 1024           // NTOT = 49*1024
#define NV8   (HWW/8)

#define EP_STORE   0
#define EP_ADDFEAT 1
#define EP_T1H     2
#define EP_DYREC   3
#define EP_DT1     4
#define EP_DYFIN   5

typedef unsigned short u16;
typedef __attribute__((ext_vector_type(8))) short bf16x8;
typedef __attribute__((ext_vector_type(4))) float f32x4;

__device__ __forceinline__ float bf2f(u16 u){
  return __uint_as_float(((unsigned)u)<<16);
}
__device__ __forceinline__ u16 f2bf(float f){
  unsigned u = __float_as_uint(f);
  u += 0x7FFFu + ((u>>16)&1u);
  return (u16)(u>>16);
}
__device__ __forceinline__ float gelu_f(float x){          // exact (output path)
  return 0.5f*x*(1.0f+erff(x*0.70710678118654752f));
}
__device__ __forceinline__ float gelu_f_fast(float x){     // tanh-approx (grad-only)
  float u = 0.7978845608f*x*(1.0f+0.044715f*x*x);
  u = fminf(fmaxf(u, -30.0f), 30.0f);
  float e = __expf(2.0f*u);
  return x*e/(e+1.0f);
}
__device__ __forceinline__ float gelu_g_fast(float x){     // d/dx tanh-approx gelu
  float x2 = x*x;
  float u = 0.7978845608f*x*(1.0f+0.044715f*x2);
  u = fminf(fmaxf(u, -30.0f), 30.0f);
  float e = __expf(2.0f*u);
  float th = (e-1.0f)/(e+1.0f);
  float sech2 = 1.0f - th*th;
  float du = 0.7978845608f*(1.0f+0.134145f*x2);
  return 0.5f*(1.0f+th) + 0.5f*x*sech2*du;
}
__device__ __forceinline__ float blk_sum(float v, float* sm){
  #pragma unroll
  for (int o=32;o>0;o>>=1) v += __shfl_down(v,o);
  if ((threadIdx.x & 63)==0) sm[threadIdx.x>>6] = v;
  __syncthreads();
  float r = sm[0]+sm[1]+sm[2]+sm[3];
  __syncthreads();
  return r;
}
__device__ __forceinline__ uint4 pack8(const ushort* e){
  uint4 v;
  v.x = (unsigned)e[0] | ((unsigned)e[1]<<16);
  v.y = (unsigned)e[2] | ((unsigned)e[3]<<16);
  v.z = (unsigned)e[4] | ((unsigned)e[5]<<16);
  v.w = (unsigned)e[6] | ((unsigned)e[7]<<16);
  return v;
}
__device__ __forceinline__ void up8(uint4 v, float* f){
  f[0]=bf2f((u16)(v.x&0xFFFFu)); f[1]=bf2f((u16)(v.x>>16));
  f[2]=bf2f((u16)(v.y&0xFFFFu)); f[3]=bf2f((u16)(v.y>>16));
  f[4]=bf2f((u16)(v.z&0xFFFFu)); f[5]=bf2f((u16)(v.z>>16));
  f[6]=bf2f((u16)(v.w&0xFFFFu)); f[7]=bf2f((u16)(v.w>>16));
}
__device__ __forceinline__ uint4 pk8(const float* f){
  uint4 v;
  v.x=(unsigned)f2bf(f[0])|((unsigned)f2bf(f[1])<<16);
  v.y=(unsigned)f2bf(f[2])|((unsigned)f2bf(f[3])<<16);
  v.z=(unsigned)f2bf(f[4])|((unsigned)f2bf(f[5])<<16);
  v.w=(unsigned)f2bf(f[6])|((unsigned)f2bf(f[7])<<16);
  return v;
}

// ---------- probes ----------
__global__ void k_detect_dtype(const u16* __restrict__ xs, int* flag){
  if (threadIdx.x || blockIdx.x) return;
  int plaus = 0;
  for (int i=0;i<256;i+=2){
    float f = bf2f(xs[i]);
    float a = fabsf(f);
    if (isfinite(f) && a < 32.0f && a > 1e-5f) plaus++;
  }
  *flag = (plaus >= 64) ? 1 : 0;
}
__global__ void k_detect_mask(const unsigned char* __restrict__ m, int* flag){
  if (threadIdx.x || blockIdx.x) return;
  unsigned char mx=0; int nz0=0,nz1=0,nz2=0,nz3=0;
  for (int i=0;i<256;i++){
    unsigned char v=m[i]; if (v>mx) mx=v;
    if (v){ int r=i&3; if(r==0)nz0=1; else if(r==1)nz1=1; else if(r==2)nz2=1; else nz3=1; }
  }
  int f;
  if (mx<=1) f = (nz1|nz2|nz3) ? 0 : 1;
  else       f = (!nz0 && !nz1) ? 3 : 2;
  *flag=f;
}
__global__ void k_report(u16* out, float v){
  if (threadIdx.x==0 && blockIdx.x==0) out[0] = f2bf(v);
}

__global__ void k_cvt(const void* __restrict__ src, float* __restrict__ dst, int n,
                      const int* __restrict__ dtf){
  int i = blockIdx.x*256 + threadIdx.x;
  if (i>=n) return;
  if (*dtf) dst[i] = bf2f(((const u16*)src)[i]);
  else      dst[i] = ((const float*)src)[i];
}
__global__ void k_wcvt(const float* __restrict__ src, u16* __restrict__ d,
                       u16* __restrict__ dT, int R, int Cc){
  int i = blockIdx.x*256+threadIdx.x;
  if (i >= R*Cc) return;
  int r = i/Cc, c = i - r*Cc;
  u16 v = f2bf(src[i]);
  d[i] = v;
  if (dT) dT[(size_t)c*R + r] = v;
}
// x -> bf16 arena (8 elems/thread)
__global__ void k_xcvt(const void* __restrict__ xv, const int* __restrict__ dtf,
                       u16* __restrict__ xb){
  size_t i8 = (size_t)blockIdx.x*256+threadIdx.x;
  if (*dtf){
    ((uint4*)xb)[i8] = ((const uint4*)xv)[i8];
  } else {
    float4 a = ((const float4*)xv)[2*i8];
    float4 b = ((const float4*)xv)[2*i8+1];
    float f[8] = {a.x,a.y,a.z,a.w,b.x,b.y,b.z,b.w};
    ((uint4*)xb)[i8] = pk8(f);
  }
}

__global__ void k_expand(const unsigned char* __restrict__ mraw, const int* __restrict__ flag,
                         float* __restrict__ mf, float* __restrict__ zc){
  __shared__ float sm[4];
  int i = blockIdx.x*256 + threadIdx.x;
  int f = *flag;
  float v;
  if (f==1)      v = (((const int*)mraw)[i] != 0) ? 1.f : 0.f;
  else if (f==0) v = (mraw[i] != 0) ? 1.f : 0.f;
  else if (f==2) v = (((const u16*)mraw)[i] != 0) ? 1.f : 0.f;
  else           v = (((const float*)mraw)[i] != 0.f) ? 1.f : 0.f;
  mf[i] = v;
  float S = blk_sum(1.f - v, sm);
  if (threadIdx.x==0) atomicAdd(&zc[blockIdx.x/196], S);
}

// ---------- 64-row MFMA GEMM (M=64 cases: T1H, DT1) ----------
template<int MASKX,int EPI>
__global__ __launch_bounds__(256) void k_gemm64(
    const u16* __restrict__ A, const u16* __restrict__ Xb, u16* __restrict__ Out,
    int K, const float* __restrict__ mf, const u16* __restrict__ e0,
    u16* __restrict__ o2)
{
  __shared__ u16 Ws[64*40];
  __shared__ u16 Xs[128*40];
  const int t = threadIdx.x;
  const int w = t >> 6, lane = t & 63;
  const int col = lane & 15, quad = lane >> 4;
  const int M = 64;
  const int n0 = blockIdx.x << 7;
  const int wrow = t >> 2, wkq = (t & 3) * 8;
  const int xn   = 2*(t & 63);
  const int xq   = t >> 6;
  const int gn0  = n0 + xn;
  const int xb_  = gn0 / HWW;
  const int xs_  = gn0 - xb_*HWW;

  f32x4 acc[4][2];
  #pragma unroll
  for (int i=0;i<4;i++){
    #pragma unroll
    for (int j=0;j<2;j++) acc[i][j] = (f32x4)(0.0f);
  }
  for (int k0=0; k0<K; k0+=32){
    {
      uint4 v = *(const uint4*)(A + (size_t)wrow*K + k0 + wkq);
      *(uint4*)(Ws + wrow*40 + wkq) = v;
    }
    {
      ushort e[16];
      size_t base = ((size_t)xb_*K + k0 + xq*8)*HWW + xs_;
      #pragma unroll
      for (int j=0;j<8;j++){
        unsigned v = *(const unsigned*)(Xb + base + (size_t)j*HWW);
        e[j]   = (ushort)(v & 0xFFFFu);
        e[8+j] = (ushort)(v >> 16);
      }
      if (MASKX){
        if (mf[gn0]   == 0.f){
          #pragma unroll
          for (int j=0;j<8;j++) e[j] = 0;
        }
        if (mf[gn0+1] == 0.f){
          #pragma unroll
          for (int j=0;j<8;j++) e[8+j] = 0;
        }
      }
      *(uint4*)(Xs + xn*40     + xq*8) = pack8(e);
      *(uint4*)(Xs + (xn+1)*40 + xq*8) = pack8(e+8);
    }
    __syncthreads();
    bf16x8 af[4], bfr[2];
    #pragma unroll
    for (int mi=0;mi<4;mi++)
      af[mi] = *(const bf16x8*)(Ws + (mi*16+col)*40 + quad*8);
    #pragma unroll
    for (int nj=0;nj<2;nj++)
      bfr[nj] = *(const bf16x8*)(Xs + (w*32+nj*16+col)*40 + quad*8);
    #pragma unroll
    for (int mi=0;mi<4;mi++){
      #pragma unroll
      for (int nj=0;nj<2;nj++)
        acc[mi][nj] = __builtin_amdgcn_mfma_f32_16x16x32_bf16(af[mi], bfr[nj], acc[mi][nj], 0,0,0);
    }
    __syncthreads();
  }
  #pragma unroll
  for (int nj=0;nj<2;nj++){
    const int nb = n0 + w*32 + nj*16;
    const int b  = nb / HWW;
    const int sb = nb - b*HWW + col;
    #pragma unroll
    for (int mi=0;mi<4;mi++){
      #pragma unroll
      for (int r=0;r<4;r++){
        const int m = mi*16 + quad*4 + r;
        const size_t oidx = ((size_t)b*M + m)*HWW + sb;
        float v = acc[mi][nj][r];
        if (EPI==EP_T1H){ Out[oidx] = f2bf(v); o2[oidx] = f2bf(gelu_f_fast(v)); }
        else if (EPI==EP_DT1){ Out[oidx] = f2bf(v * gelu_g_fast(bf2f(e0[oidx]))); }
        else { Out[oidx] = f2bf(v); }
      }
    }
  }
}

// ---------- 128x128 MFMA GEMM: Out[m,n] = sum_k A[m,k]*X[k,n] ----------
template<int EPI,int XDYN,int E0DYN>
__global__ __launch_bounds__(256) void k_gemm128(
    const u16* __restrict__ A, const void* __restrict__ Xv, u16* __restrict__ Out,
    int K, const int* __restrict__ xdt, const float* __restrict__ mf,
    const void* __restrict__ e0, const float* __restrict__ e1,
    const float* __restrict__ e2)
{
  __shared__ u16 Ws[128*40];
  __shared__ u16 Xs[128*40];
  const int t = threadIdx.x;
  const int w = t >> 6, lane = t & 63;
  const int col = lane & 15, quad = lane >> 4;
  const int wm = w & 1, wn = w >> 1;
  const int M = (int)gridDim.y << 7;
  const int m0 = blockIdx.y << 7, n0 = blockIdx.x << 7;
  const int isbx = XDYN ? *xdt : 1;
  const u16*   Xb = (const u16*)Xv;
  const float* Xf = (const float*)Xv;
  const int wrow = t >> 1, wkq = (t & 1) * 16;
  const int xn   = 2*(t & 63);
  const int xq   = t >> 6;
  const int gn0  = n0 + xn;
  const int xb_  = gn0 / HWW;
  const int xs_  = gn0 - xb_*HWW;

  f32x4 acc[4][4];
  #pragma unroll
  for (int i=0;i<4;i++){
    #pragma unroll
    for (int j=0;j<4;j++) acc[i][j] = (f32x4)(0.0f);
  }

  for (int k0=0; k0<K; k0+=32){
    {
      const u16* src = A + (size_t)(m0+wrow)*K + k0 + wkq;
      *(uint4*)(Ws + wrow*40 + wkq)     = *(const uint4*)(src);
      *(uint4*)(Ws + wrow*40 + wkq + 8) = *(const uint4*)(src + 8);
    }
    {
      ushort e[16];
      size_t base = ((size_t)xb_*K + k0 + xq*8)*HWW + xs_;
      if (isbx){
        #pragma unroll
        for (int j=0;j<8;j++){
          unsigned v = *(const unsigned*)(Xb + base + (size_t)j*HWW);
          e[j]   = (ushort)(v & 0xFFFFu);
          e[8+j] = (ushort)(v >> 16);
        }
      } else {
        #pragma unroll
        for (int j=0;j<8;j++){
          float2 f = *(const float2*)(Xf + base + (size_t)j*HWW);
          e[j]   = f2bf(f.x);
          e[8+j] = f2bf(f.y);
        }
      }
      *(uint4*)(Xs + xn*40     + xq*8) = pack8(e);
      *(uint4*)(Xs + (xn+1)*40 + xq*8) = pack8(e+8);
    }
    __syncthreads();
    bf16x8 af[4], bfr[4];
    #pragma unroll
    for (int mi=0;mi<4;mi++)
      af[mi] = *(const bf16x8*)(Ws + (wm*64 + mi*16 + col)*40 + quad*8);
    #pragma unroll
    for (int nj=0;nj<4;nj++)
      bfr[nj] = *(const bf16x8*)(Xs + (wn*64 + nj*16 + col)*40 + quad*8);
    #pragma unroll
    for (int mi=0;mi<4;mi++){
      #pragma unroll
      for (int nj=0;nj<4;nj++)
        acc[mi][nj] = __builtin_amdgcn_mfma_f32_16x16x32_bf16(af[mi], bfr[nj], acc[mi][nj], 0,0,0);
    }
    __syncthreads();
  }

  const int isb0 = E0DYN ? *xdt : 1;
  float dscale = 0.f;
  if (EPI==EP_DYREC) dscale = 2.0f / (e1[0]*(float)CC + 1e-8f);
  #pragma unroll
  for (int nj=0;nj<4;nj++){
    const int nb = n0 + wn*64 + nj*16;
    const int b  = nb / HWW;
    const int sb = nb - b*HWW + col;
    const int n  = nb + col;
    #pragma unroll
    for (int mi=0;mi<4;mi++){
      #pragma unroll
      for (int r=0;r<4;r++){
        const int m = m0 + wm*64 + mi*16 + quad*4 + r;
        const size_t oidx = ((size_t)b*M + m)*HWW + sb;
        float v = acc[mi][nj][r];
        if (EPI==EP_STORE){ Out[oidx] = f2bf(v); }
        else if (EPI==EP_ADDFEAT){
          float xv = isb0 ? bf2f(((const u16*)e0)[oidx]) : ((const float*)e0)[oidx];
          Out[oidx] = f2bf(v + xv);
        }
        else if (EPI==EP_DYREC){
          float iv = 1.0f - mf[n];
          Out[oidx] = f2bf((v - bf2f(((const u16*)e0)[oidx]))*iv*dscale);
        }
        else if (EPI==EP_DYFIN){
          float dyold = bf2f(Out[oidx]);
          Out[oidx] = f2bf(mf[n]*v - dyold + e1[m] + e2[m]*bf2f(((const u16*)e0)[oidx]));
        }
      }
    }
  }
}

// ---------- 128x128 MFMA weight-grad, split-K 49 ----------
template<int QDYN>
__global__ __launch_bounds__(256) void k_wgrad128(
    const u16* __restrict__ P, const void* __restrict__ Qv, float* __restrict__ part,
    int CHP, int CHQ, const int* __restrict__ xdt)
{
  __shared__ u16 Ps[128*40];
  __shared__ u16 Qs[128*40];
  const int t = threadIdx.x;
  const int w = t >> 6, lane = t & 63;
  const int col = lane & 15, quad = lane >> 4;
  const int wm = w & 1, wn = w >> 1;
  const int m0 = blockIdx.x << 7, n0 = blockIdx.y << 7;
  const int sk = blockIdx.z;
  const int isbq = QDYN ? *xdt : 1;
  const u16*   Qb = (const u16*)Qv;
  const float* Qf = (const float*)Qv;
  const int srow = t & 127;
  f32x4 acc[4][4];
  #pragma unroll
  for (int i=0;i<4;i++){
    #pragma unroll
    for (int j=0;j<4;j++) acc[i][j] = (f32x4)(0.0f);
  }

  for (int kb = sk*WCHUNK; kb < sk*WCHUNK + WCHUNK; kb += 32){
    const int b = kb / HWW;
    const int s = kb - b*HWW;
    if (t < 128){
      size_t off = ((size_t)b*CHP + m0+srow)*HWW + s;
      *(uint4*)(Ps + srow*40)      = *(const uint4*)(P + off);
      *(uint4*)(Ps + srow*40 + 8)  = *(const uint4*)(P + off + 8);
      *(uint4*)(Ps + srow*40 + 16) = *(const uint4*)(P + off + 16);
      *(uint4*)(Ps + srow*40 + 24) = *(const uint4*)(P + off + 24);
    } else {
      size_t off = ((size_t)b*CHQ + n0+srow)*HWW + s;
      if (isbq){
        *(uint4*)(Qs + srow*40)      = *(const uint4*)(Qb + off);
        *(uint4*)(Qs + srow*40 + 8)  = *(const uint4*)(Qb + off + 8);
        *(uint4*)(Qs + srow*40 + 16) = *(const uint4*)(Qb + off + 16);
        *(uint4*)(Qs + srow*40 + 24) = *(const uint4*)(Qb + off + 24);
      } else {
        #pragma unroll
        for (int h=0; h<2; h++){
          ushort e[16];
          #pragma unroll
          for (int g=0; g<4; g++){
            float4 f = *(const float4*)(Qf + off + h*16 + g*4);
            e[g*4+0]=f2bf(f.x); e[g*4+1]=f2bf(f.y); e[g*4+2]=f2bf(f.z); e[g*4+3]=f2bf(f.w);
          }
          *(uint4*)(Qs + srow*40 + h*16)     = pack8(e);
          *(uint4*)(Qs + srow*40 + h*16 + 8) = pack8(e+8);
        }
      }
    }
    __syncthreads();
    bf16x8 pa[4], qb[4];
    #pragma unroll
    for (int a=0;a<4;a++)
      pa[a] = *(const bf16x8*)(Ps + (wm*64 + a*16 + col)*40 + quad*8);
    #pragma unroll
    for (int bb=0;bb<4;bb++)
      qb[bb] = *(const bf16x8*)(Qs + (wn*64 + bb*16 + col)*40 + quad*8);
    #pragma unroll
    for (int a=0;a<4;a++){
      #pragma unroll
      for (int bb=0;bb<4;bb++)
        acc[a][bb] = __builtin_amdgcn_mfma_f32_16x16x32_bf16(pa[a], qb[bb], acc[a][bb], 0,0,0);
    }
    __syncthreads();
  }
  float* dst = part + (size_t)sk*CHP*CHQ;
  #pragma unroll
  for (int a=0;a<4;a++){
    #pragma unroll
    for (int bb=0;bb<4;bb++){
      #pragma unroll
      for (int r=0;r<4;r++){
        const int m = m0 + wm*64 + a*16 + quad*4 + r;
        const int n = n0 + wn*64 + bb*16 + col;
        dst[(size_t)m*CHQ + n] = acc[a][bb][r];
      }
    }
  }
}
__global__ void k_wgrad_reduce(const float* __restrict__ part, float* __restrict__ dW, int n){
  int i = blockIdx.x*256+threadIdx.x;
  if (i>=n) return;
  float s=0;
  #pragma unroll
  for (int k=0;k<SKW;k++) s += part[(size_t)k*n + i];
  dW[i]=s;
}

// ---------- GroupNorm fwd ----------
__global__ void k_gn_stats(const u16* __restrict__ h1, float* gsum, float* gsumsq){
  __shared__ float sm[4];
  int bo = blockIdx.x;
  const uint4* p = (const uint4*)(h1 + (size_t)bo*HWW);
  float s=0, ss=0;
  for (int i=threadIdx.x;i<NV8;i+=256){
    float f[8]; up8(p[i], f);
    #pragma unroll
    for (int j=0;j<8;j++){ s+=f[j]; ss=fmaf(f[j],f[j],ss); }
  }
  float S  = blk_sum(s, sm);
  float SS = blk_sum(ss, sm);
  if (threadIdx.x==0){
    int b = bo>>9, o = bo&511;
    int bg = b*NGRP + (o>>6);
    atomicAdd(&gsum[bg], S);
    atomicAdd(&gsumsq[bg], SS);
  }
}
__global__ void k_gn_finalize(const float* gsum, const float* gsumsq, float* mu, float* rsig){
  int i = threadIdx.x; if (i>=BB*NGRP) return;
  float m = gsum[i]*(1.0f/GMSZ);
  float v = gsumsq[i]*(1.0f/GMSZ) - m*m;
  v = fmaxf(v, 0.0f);
  mu[i]=m; rsig[i]=rsqrtf(v+1e-5f);
}
template<int FAST>
__global__ void k_gelu_fwd(const u16* __restrict__ src, u16* __restrict__ dst,
    const float* __restrict__ mu, const float* __restrict__ rsig,
    const float* __restrict__ pg, const float* __restrict__ pb){
  int bo = blockIdx.x;
  int b = bo>>9, o = bo&511, bg = b*NGRP + (o>>6);
  float m = mu[bg], r = rsig[bg], g = pg[o], be = pb[o];
  const uint4* ps = (const uint4*)(src + (size_t)bo*HWW);
  uint4* pd = (uint4*)(dst + (size_t)bo*HWW);
  for (int i=threadIdx.x;i<NV8;i+=256){
    float f[8]; up8(ps[i], f);
    #pragma unroll
    for (int j=0;j<8;j++){
      float gh = fmaf((f[j]-m)*r, g, be);
      f[j] = FAST ? gelu_f_fast(gh) : gelu_f(gh);
    }
    pd[i] = pk8(f);
  }
}

// ---------- y channel moments ----------
__global__ void k_y_stats(const u16* __restrict__ y, float* cmsum, float* cmsq){
  __shared__ float sm[4];
  int bc = blockIdx.x;
  const uint4* p = (const uint4*)(y + (size_t)bc*HWW);
  float s=0, ss=0;
  for (int i=threadIdx.x;i<NV8;i+=256){
    float f[8]; up8(p[i], f);
    #pragma unroll
    for (int j=0;j<8;j++){ s+=f[j]; ss=fmaf(f[j],f[j],ss); }
  }
  float S  = blk_sum(s, sm);
  float SS = blk_sum(ss, sm);
  if (threadIdx.x==0){
    int c = bc & 255;
    atomicAdd(&cmsum[c], S);
    atomicAdd(&cmsq[c], SS);
  }
}
__global__ void k_y_finalize(const float* cmsum, const float* cmsq,
    const float* rmf, const float* rvf, float* coefA, float* coefB){
  int c = threadIdx.x; if (c>=CC) return;
  float cm = cmsum[c]*(1.0f/NTOT);
  float cv = (cmsq[c] - (float)NTOT*cm*cm)*(1.0f/(NTOT-1));
  float rvp = rvf[c] + 1e-8f;
  float gcm = 0.2f*(cm - rmf[c])*(1.0f/CC);
  float gcv = 0.2f*(cv/rvp - 1.0f)/(rvp*(float)CC);
  coefA[c] = gcm*(1.0f/NTOT) - 2.0f*gcv*cm*(1.0f/(NTOT-1));
  coefB[c] = 2.0f*gcv*(1.0f/(NTOT-1));
}

// ---------- GroupNorm backward ----------
__global__ void k_gn_bwd1(u16* __restrict__ dA, const u16* __restrict__ h1,
    const float* mu, const float* rsig, const float* pg, const float* pb,
    float* dGa, float* dBe, float* s1, float* s2){
  __shared__ float sm[4];
  int bo = blockIdx.x;
  int b = bo>>9, o = bo&511, bg = b*NGRP + (o>>6);
  float m = mu[bg], r = rsig[bg], g = pg[o], be = pb[o];
  uint4* pa = (uint4*)(dA + (size_t)bo*HWW);
  const uint4* ph = (const uint4*)(h1 + (size_t)bo*HWW);
  float sb=0, sg=0, t1=0, t2=0;
  for (int i=threadIdx.x;i<NV8;i+=256){
    float fa[8], fh[8]; up8(pa[i], fa); up8(ph[i], fh);
    #pragma unroll
    for (int j=0;j<8;j++){
      float hn = (fh[j]-m)*r;
      float ghat = fmaf(hn,g,be);
      float dgh = fa[j]*gelu_g_fast(ghat);
      float dhn = dgh*g;
      fa[j] = dhn;
      sb += dgh; sg = fmaf(dgh,hn,sg); t1 += dhn; t2 = fmaf(dhn,hn,t2);
    }
    pa[i] = pk8(fa);
  }
  float S;
  S = blk_sum(sb,sm); if (threadIdx.x==0) atomicAdd(&dBe[o], S);
  S = blk_sum(sg,sm); if (threadIdx.x==0) atomicAdd(&dGa[o], S);
  S = blk_sum(t1,sm); if (threadIdx.x==0) atomicAdd(&s1[bg], S);
  S = blk_sum(t2,sm); if (threadIdx.x==0) atomicAdd(&s2[bg], S);
}
__global__ void k_gn_bwd2(u16* __restrict__ dA, const u16* __restrict__ h1,
    const float* mu, const float* rsig, const float* s1, const float* s2){
  int bo = blockIdx.x;
  int b = bo>>9, o = bo&511, bg = b*NGRP + (o>>6);
  float m = mu[bg], r = rsig[bg];
  float a1 = s1[bg]*(1.0f/GMSZ), a2 = s2[bg]*(1.0f/GMSZ);
  uint4* pa = (uint4*)(dA + (size_t)bo*HWW);
  const uint4* ph = (const uint4*)(h1 + (size_t)bo*HWW);
  for (int i=threadIdx.x;i<NV8;i+=256){
    float fa[8], fh[8]; up8(pa[i], fa); up8(ph[i], fh);
    #pragma unroll
    for (int j=0;j<8;j++){
      float hn = (fh[j]-m)*r;
      fa[j] = r*(fa[j] - a1 - hn*a2);
    }
    pa[i] = pk8(fa);
  }
}

__global__ void k_update(float* pw1, float* pw2, float* pg, float* pb,
    const float* dW1, const float* dW2, const float* dGa, const float* dBe){
  int i = blockIdx.x*256+threadIdx.x;
  if (i < HIDD*CC){ pw1[i] -= LRATE*dW1[i]; pw2[i] -= LRATE*dW2[i]; }
  if (i < HIDD){ pg[i] -= LRATE*dGa[i]; pb[i] -= LRATE*dBe[i]; }
}

// ---------- gate + output ----------
__global__ void k_pool(const void* __restrict__ xv, const int* __restrict__ dtf,
                       float* pooled, int forceb){
  __shared__ float sm[4];
  int bc = blockIdx.x;
  int isb = forceb ? 1 : *dtf;
  float s=0;
  if (isb){
    const uint4* p = (const uint4*)((const u16*)xv + (size_t)bc*HWW);
    for (int i=threadIdx.x;i<NV8;i+=256){
      float f[8]; up8(p[i], f);
      #pragma unroll
      for (int j=0;j<8;j++) s+=f[j];
    }
  } else {
    const float4* p = (const float4*)((const float*)xv + (size_t)bc*HWW);
    for (int i=threadIdx.x;i<HWW/4;i+=256){
      float4 f = p[i];
      s += f.x+f.y+f.z+f.w;
    }
  }
  float S = blk_sum(s,sm);
  if (threadIdx.x==0) pooled[bc]=S*(1.0f/HWW);
}
__global__ void k_gate(const float* __restrict__ pooled, const float* __restrict__ gw1,
    const float* __restrict__ gb1, const float* __restrict__ gw2, const float* __restrict__ gb2,
    float* gate){
  int b = blockIdx.x, j = threadIdx.x;
  float acc = gb1[j];
  const float* pr = pooled + b*CC;
  for (int c=0;c<CC;c++) acc = fmaf(pr[c], gw1[j*CC+c], acc);
  float v = gelu_f(acc)*gw2[j];
  #pragma unroll
  for (int o=32;o>0;o>>=1) v += __shfl_down(v,o);
  if (j==0) gate[b] = 1.0f/(1.0f+expf(-(v+gb2[0])));
}
__global__ void k_out(const void* __restrict__ xv, const u16* __restrict__ mod,
    const float* __restrict__ gate, const float* __restrict__ rsf,
    const int* __restrict__ dtf, void* __restrict__ out){
  size_t i4 = (size_t)blockIdx.x*256+threadIdx.x;
  size_t i = i4*4;
  int b = (int)(i / ((size_t)CC*HWW));
  float gm = rsf[0]*gate[b];
  int isb = *dtf;
  ushort4 mv = ((const ushort4*)mod)[i4];
  if (isb){
    ushort4 xu = ((const ushort4*)xv)[i4];
    ushort4 r;
    r.x = f2bf(bf2f(xu.x) + gm*bf2f(mv.x));
    r.y = f2bf(bf2f(xu.y) + gm*bf2f(mv.y));
    r.z = f2bf(bf2f(xu.z) + gm*bf2f(mv.z));
    r.w = f2bf(bf2f(xu.w) + gm*bf2f(mv.w));
    ((ushort4*)out)[i4] = r;
  } else {
    float4 xf = ((const float4*)xv)[i4];
    float4 r;
    r.x = xf.x + gm*bf2f(mv.x);
    r.y = xf.y + gm*bf2f(mv.y);
    r.z = xf.z + gm*bf2f(mv.z);
    r.w = xf.w + gm*bf2f(mv.w);
    ((float4*)out)[i4] = r;
  }
}

// =======================================================================
extern "C" void kernel_launch(void* const* d_in, const int* in_sizes, int n_in,
                              void* d_out, int out_size, void* d_ws, size_t ws_size,
                              hipStream_t stream)
{
  const void* x_in   = d_in[0];
  const void* w1_in  = d_in[1];
  const void* g_in   = d_in[2];
  const void* b_in   = d_in[3];
  const void* w2_in  = d_in[4];
  const void* rw1_in = d_in[5];
  const void* rw2_in = d_in[6];
  const void* gw1_in = d_in[7];
  const void* gb1_in = d_in[8];
  const void* gw2_in = d_in[9];
  const void* gb2_in = d_in[10];
  const void* rs_in  = d_in[11];
  const void* rm_in  = d_in[12];
  const void* rv_in  = d_in[13];
  const void* mk_in  = d_in[14];
  (void)in_sizes; (void)n_in; (void)out_size;

  char* base = (char*)d_ws;
  size_t off = 0;
  auto alloc = [&](size_t bytes)->char*{
    char* p = base+off; off = (off+bytes+255)&~(size_t)255; return p;
  };
  u16* ybuf = (u16*)alloc((size_t)CC*NTOT*2);     // 25.69 MB  y / h1rc-lo / wgrad part (exact fit)
  u16* dY   = (u16*)alloc((size_t)CC*NTOT*2);     // 25.69 MB  dY / h1rc-hi
  u16* Ab   = (u16*)alloc((size_t)HIDD*NTOT*2);   // 51.4 MB   h1 -> a -> dA -> dH1
  u16* t1b  = (u16*)alloc((size_t)C4*NTOT*2);     // 6.4 MB
  u16* hb   = (u16*)alloc((size_t)C4*NTOT*2);     // 6.4 MB
  u16* h1rc = ybuf;
  float* part = (float*)ybuf;                     // SKW*131072*4 = 25.69MB == ybuf
  float* mfb  = (float*)alloc((size_t)2*NTOT*4);
  float* pw1  = (float*)alloc(131072*4);
  float* pw2  = (float*)alloc(131072*4);
  float* dW1  = (float*)alloc(131072*4);
  float* dW2  = (float*)alloc(131072*4);
  u16* wb1   = (u16*)alloc(131072*2);
  u16* wb2   = (u16*)alloc(131072*2);
  u16* wb2T  = (u16*)alloc(131072*2);
  u16* rwb1  = (u16*)alloc(16384*2);
  u16* rwb1T = (u16*)alloc(16384*2);
  u16* rwb2  = (u16*)alloc(16384*2);
  u16* rwb2T = (u16*)alloc(16384*2);
  float* pg   = (float*)alloc(512*4);
  float* pb   = (float*)alloc(512*4);
  float* rw1f = (float*)alloc(16384*4);
  float* rw2f = (float*)alloc(16384*4);
  float* gw1f = (float*)alloc(16384*4);
  float* gb1f = (float*)alloc(64*4);
  float* gw2f = (float*)alloc(64*4);
  float* gb2f = (float*)alloc(256);
  float* rmf  = (float*)alloc(256*4);
  float* rvf  = (float*)alloc(256*4);
  float* rsf  = (float*)alloc(256);
  float* gsum   = (float*)alloc(512);
  float* gsumsq = (float*)alloc(512);
  float* mu     = (float*)alloc(512);
  float* rsig   = (float*)alloc(512);
  float* cmsum  = (float*)alloc(1024);
  float* cmsq   = (float*)alloc(1024);
  float* coefA  = (float*)alloc(1024);
  float* coefB  = (float*)alloc(1024);
  float* dGa    = (float*)alloc(2048);
  float* dBe    = (float*)alloc(2048);
  float* s1     = (float*)alloc(512);
  float* s2     = (float*)alloc(512);
  float* pooled = (float*)alloc(16384);
  float* gate   = (float*)alloc(256);
  float* zc     = (float*)alloc(256);
  int*   dtf    = (int*)alloc(256);
  int*   mkf    = (int*)alloc(256);

  if (off > ws_size){
    k_report<<<1,64,0,stream>>>((u16*)d_out, (float)(ws_size>>20));
    return;
  }
  // optional arenas, priority order (ws_size constant per-harness -> graph-safe):
  u16* xb = nullptr;                              // bf16 x copy: +25.69 MB
  if (off + (size_t)CC*NTOT*2 <= ws_size) xb = (u16*)alloc((size_t)CC*NTOT*2);
  u16* h1p = nullptr;                             // persistent h1: +51.4 MB
  if (off + (size_t)HIDD*NTOT*2 <= ws_size) h1p = (u16*)alloc((size_t)HIDD*NTOT*2);

  // ---- probes + param conversion ----
  k_detect_dtype<<<1,1,0,stream>>>((const u16*)x_in, dtf);
  k_detect_mask<<<1,1,0,stream>>>((const unsigned char*)mk_in, mkf);
  #define CVT(src,dst,n) k_cvt<<<((n)+255)/256,256,0,stream>>>(src,dst,(n),dtf)
  CVT(w1_in,  pw1,  131072);
  CVT(g_in,   pg,   512);
  CVT(b_in,   pb,   512);
  CVT(w2_in,  pw2,  131072);
  CVT(rw1_in, rw1f, 16384);
  CVT(rw2_in, rw2f, 16384);
  CVT(gw1_in, gw1f, 16384);
  CVT(gb1_in, gb1f, 64);
  CVT(gw2_in, gw2f, 64);
  CVT(gb2_in, gb2f, 1);
  CVT(rs_in,  rsf,  1);
  CVT(rm_in,  rmf,  256);
  CVT(rv_in,  rvf,  256);
  #undef CVT
  k_wcvt<<<512,256,0,stream>>>(pw1, wb1, 0,     HIDD, CC);
  k_wcvt<<<512,256,0,stream>>>(pw2, wb2, wb2T,  CC, HIDD);
  k_wcvt<<<64,256,0,stream>>>(rw1f, rwb1, rwb1T, C4, CC);
  k_wcvt<<<64,256,0,stream>>>(rw2f, rwb2, rwb2T, CC, C4);
  if (xb) k_xcvt<<<6272,256,0,stream>>>(x_in, dtf, xb);
  hipMemsetAsync(zc, 0, 8, stream);
  k_expand<<<392,256,0,stream>>>((const unsigned char*)mk_in, mkf, mfb, zc);

  // ---- 2 inner TTT steps ----
  for (int s=0; s<2; s++){
    const float* mfs = mfb + s*NTOT;
    u16* h1dst = h1p ? h1p : Ab;
    // h1 = w1 @ x
    if (xb) k_gemm128<EP_STORE,0,0><<<dim3(392,4),256,0,stream>>>(wb1, xb,   h1dst, CC, dtf, 0,0,0,0);
    else    k_gemm128<EP_STORE,1,0><<<dim3(392,4),256,0,stream>>>(wb1, x_in, h1dst, CC, dtf, 0,0,0,0);
    hipMemsetAsync(gsum, 0, 1024, stream);
    k_gn_stats<<<BB*HIDD,256,0,stream>>>(h1dst, gsum, gsumsq);
    k_gn_finalize<<<1,128,0,stream>>>(gsum, gsumsq, mu, rsig);
    k_gelu_fwd<1><<<BB*HIDD,256,0,stream>>>(h1dst, Ab, mu, rsig, pg, pb);   // Ab = a
    // y = w2 @ a + x
    if (xb) k_gemm128<EP_ADDFEAT,0,0><<<dim3(392,2),256,0,stream>>>(wb2, Ab, ybuf, HIDD, dtf, 0, xb,   0,0);
    else    k_gemm128<EP_ADDFEAT,0,1><<<dim3(392,2),256,0,stream>>>(wb2, Ab, ybuf, HIDD, dtf, 0, x_in, 0,0);
    hipMemsetAsync(cmsum, 0, 2048, stream);
    k_y_stats<<<BB*CC,256,0,stream>>>(ybuf, cmsum, cmsq);
    k_y_finalize<<<1,256,0,stream>>>(cmsum, cmsq, rmf, rvf, coefA, coefB);
    // t1 = rw1 @ (y*mf); h = gelu_fast(t1)
    k_gemm64<1,EP_T1H><<<392,256,0,stream>>>(rwb1, ybuf, t1b, CC, mfs, 0, hb);
    // dY := g_rec = 2*(rec - y)*inv/D
    k_gemm128<EP_DYREC,0,0><<<dim3(392,2),256,0,stream>>>(rwb2, hb, dY, C4, dtf, mfs, ybuf, zc+s, 0);
    // dT1 = (rw2^T @ g_rec) * gelu'_fast(t1)
    k_gemm64<0,EP_DT1><<<392,256,0,stream>>>(rwb2T, dY, hb, CC, 0, t1b, 0);
    // dY := mf*(rw1^T @ dT1) - g_rec + coefA + coefB*y
    k_gemm128<EP_DYFIN,0,0><<<dim3(392,2),256,0,stream>>>(rwb1T, hb, dY, C4, dtf, mfs, ybuf, coefA, coefB);
    // dW2[c,o] = sum_n dY[c,n]*a[o,n]   (part overlays ybuf: y dead)
    k_wgrad128<0><<<dim3(2,4,SKW),256,0,stream>>>(dY, Ab, part, CC, HIDD, dtf);
    k_wgrad_reduce<<<512,256,0,stream>>>(part, dW2, 131072);
    // dA = w2^T @ dY  (overwrites a in Ab)
    k_gemm128<EP_STORE,0,0><<<dim3(392,4),256,0,stream>>>(wb2T, dY, Ab, CC, dtf, 0,0,0,0);
    const u16* h1src = h1p;
    if (!h1p){
      if (xb) k_gemm128<EP_STORE,0,0><<<dim3(392,4),256,0,stream>>>(wb1, xb,   h1rc, CC, dtf, 0,0,0,0);
      else    k_gemm128<EP_STORE,1,0><<<dim3(392,4),256,0,stream>>>(wb1, x_in, h1rc, CC, dtf, 0,0,0,0);
      h1src = h1rc;
    }
    hipMemsetAsync(dGa, 0, 5120, stream);
    k_gn_bwd1<<<BB*HIDD,256,0,stream>>>(Ab, h1src, mu, rsig, pg, pb, dGa, dBe, s1, s2);
    k_gn_bwd2<<<BB*HIDD,256,0,stream>>>(Ab, h1src, mu, rsig, s1, s2);
    // dW1[o,c] = sum_n dH1[o,n]*x[c,n]
    if (xb) k_wgrad128<0><<<dim3(4,2,SKW),256,0,stream>>>(Ab, xb,   part, HIDD, CC, dtf);
    else    k_wgrad128<1><<<dim3(4,2,SKW),256,0,stream>>>(Ab, x_in, part, HIDD, CC, dtf);
    k_wgrad_reduce<<<512,256,0,stream>>>(part, dW1, 131072);
    k_update<<<512,256,0,stream>>>(pw1, pw2, pg, pb, dW1, dW2, dGa, dBe);
    k_wcvt<<<512,256,0,stream>>>(pw1, wb1, 0,    HIDD, CC);
    k_wcvt<<<512,256,0,stream>>>(pw2, wb2, wb2T, CC, HIDD);
  }

  // ---- final modifier forward with updated params (exact gelu) ----
  if (xb) k_gemm128<EP_STORE,0,0><<<dim3(392,4),256,0,stream>>>(wb1, xb,   Ab, CC, dtf, 0,0,0,0);
  else    k_gemm128<EP_STORE,1,0><<<dim3(392,4),256,0,stream>>>(wb1, x_in, Ab, CC, dtf, 0,0,0,0);
  hipMemsetAsync(gsum, 0, 1024, stream);
  k_gn_stats<<<BB*HIDD,256,0,stream>>>(Ab, gsum, gsumsq);
  k_gn_finalize<<<1,128,0,stream>>>(gsum, gsumsq, mu, rsig);
  k_gelu_fwd<0><<<BB*HIDD,256,0,stream>>>(Ab, Ab, mu, rsig, pg, pb);
  k_gemm128<EP_STORE,0,0><<<dim3(392,2),256,0,stream>>>(wb2, Ab, ybuf, HIDD, dtf, 0,0,0,0);

  // ---- gate + residual merge ----
  if (xb) k_pool<<<BB*CC,256,0,stream>>>(xb, dtf, pooled, 1);
  else    k_pool<<<BB*CC,256,0,stream>>>(x_in, dtf, pooled, 0);
  k_gate<<<BB,64,0,stream>>>(pooled, gw1f, gb1f, gw2f, gb2f, gate);
  k_out<<<(CC*NTOT)/1024,256,0,stream>>>(x_in, ybuf, gate, rsf, dtf, d_out);
}